// Round 10
// baseline (315.971 us; speedup 1.0000x reference)
//
#include <hip/hip_runtime.h>
#include <hip/hip_bf16.h>
#include <math.h>

#define NB 4
#define NN 1024
#define DIMD 512
#define NH 8
#define DHD 64
#define INNERD 512
#define SCALE 0.125f
#define TEMPP 0.1f
#define KREG 0.3f
#define LNEG -23.025850929940457f

typedef __attribute__((ext_vector_type(8))) short bf16x8;
typedef __attribute__((ext_vector_type(4))) short bf16x4;
typedef __attribute__((ext_vector_type(4))) float f32x4;

static __device__ __forceinline__ short f2bf(float f) {
  unsigned u = __float_as_uint(f);
  u += 0x7fffu + ((u >> 16) & 1u);
  return (short)(u >> 16);
}
static __device__ __forceinline__ float bf2f(short s) {
  unsigned u = ((unsigned)(unsigned short)s) << 16;
  return __uint_as_float(u);
}

static __device__ __forceinline__ float wave_sum(float v) {
#pragma unroll
  for (int o = 1; o < 64; o <<= 1) v += __shfl_xor(v, o, 64);
  return v;
}

// ---------------------------------------------------------------------------
// K0: convert x, Wq|Wk|Wv (stacked), Wo to bf16. grid (3072), 256 thr.
// ---------------------------------------------------------------------------
__global__ __launch_bounds__(256) void k_pre(
    const float* __restrict__ x, const float* __restrict__ Wq,
    const float* __restrict__ Wk, const float* __restrict__ Wv,
    const float* __restrict__ Wo,
    short* __restrict__ xb, short* __restrict__ WB, short* __restrict__ WoB) {
  const int idx = blockIdx.x * 256 + threadIdx.x;
  const float* src;
  short* dst;
  int soff, doff;
  if (idx < 524288) {                       // x: 2M f32
    src = x; dst = xb; soff = doff = idx * 4;
  } else if (idx < 720896) {                // Wq|Wk|Wv: 3 x 256K f32
    const int j = idx - 524288;
    const int ww = j >> 16;
    src = (ww == 0) ? Wq : (ww == 1) ? Wk : Wv;
    soff = (j & 65535) * 4;
    dst = WB; doff = j * 4;
  } else {                                  // Wo: 256K f32
    const int j = idx - 720896;
    src = Wo; dst = WoB; soff = doff = j * 4;
  }
  const f32x4 v = *reinterpret_cast<const f32x4*>(&src[soff]);
  bf16x4 p;
#pragma unroll
  for (int e = 0; e < 4; ++e) p[e] = f2bf(v[e]);
  *reinterpret_cast<bf16x4*>(&dst[doff]) = p;
}

// ---------------------------------------------------------------------------
// K1: QKV projection as direct-fragment bf16 GEMM (no LDS, no barriers).
// M=4096 (x rows), N=1536 (q|k|v out channels), K=512. 128x128 tiles,
// 4 waves in 2x2, each wave 64x64 via acc[4][4]. Epilogue: bias, write
// Q/K (B,H,N,DH) bf16, V TRANSPOSED (B,H,DH,N), norms qn/kn from f32,
// atomicMin(kminU) for the softmax bound. grid (32, 12).
// ---------------------------------------------------------------------------
__global__ __launch_bounds__(256) void k_qkv2(
    const short* __restrict__ xb, const short* __restrict__ WB,
    const float* __restrict__ bq, const float* __restrict__ bk,
    const float* __restrict__ bv,
    short* __restrict__ Qb, short* __restrict__ Kb, short* __restrict__ VbT,
    float* __restrict__ qn, float* __restrict__ kn,
    unsigned* __restrict__ kminU) {
  const int tid = threadIdx.x;
  const int lane = tid & 63;
  const int w = tid >> 6;
  const int wr = w >> 1, wc = w & 1;
  const int lr = lane & 15, lk = lane >> 4;
  const int m0 = blockIdx.x * 128;
  const int n0 = blockIdx.y * 128;

  const short* abase = &xb[(long)(m0 + wr * 64 + lr) * DIMD + lk * 8];
  const short* bbase = &WB[(long)(n0 + wc * 64 + lr) * DIMD + lk * 8];

  const f32x4 z4 = {0.f, 0.f, 0.f, 0.f};
  f32x4 acc[4][4] = {{z4, z4, z4, z4}, {z4, z4, z4, z4},
                     {z4, z4, z4, z4}, {z4, z4, z4, z4}};

  for (int ks = 0; ks < 16; ++ks) {
    const int ko = ks * 32;
    bf16x8 af[4], bfr[4];
#pragma unroll
    for (int t = 0; t < 4; ++t) {
      af[t] = *reinterpret_cast<const bf16x8*>(&abase[t * 16 * DIMD + ko]);
      bfr[t] = *reinterpret_cast<const bf16x8*>(&bbase[t * 16 * DIMD + ko]);
    }
#pragma unroll
    for (int ar = 0; ar < 4; ++ar)
#pragma unroll
      for (int ac = 0; ac < 4; ++ac)
        acc[ar][ac] =
            __builtin_amdgcn_mfma_f32_16x16x32_bf16(af[ar], bfr[ac], acc[ar][ac], 0, 0, 0);
  }

  const int ncb = n0 + wc * 64;      // wave col base; one head per wave
  const int which = ncb >> 9;        // 0=q 1=k 2=v
  const int h = (ncb >> 6) & 7;
  const int b = m0 >> 10;
  const int bh = b * NH + h;
  const float* bias = (which == 0) ? bq : (which == 1) ? bk : bv;
  short* Out = (which == 0) ? Qb : Kb;
  const int rbase = (m0 & (NN - 1)) + wr * 64 + lk * 4;

  float p2[4][4];
#pragma unroll
  for (int ar = 0; ar < 4; ++ar)
#pragma unroll
    for (int i = 0; i < 4; ++i) p2[ar][i] = 0.f;

#pragma unroll
  for (int ac = 0; ac < 4; ++ac) {
    const int d = ac * 16 + lr;               // 0..63 within head
    const float bval = bias[h * 64 + d];
#pragma unroll
    for (int ar = 0; ar < 4; ++ar) {
#pragma unroll
      for (int i = 0; i < 4; ++i) {
        const float val = acc[ar][ac][i] + bval;
        p2[ar][i] += val * val;
        const int rowIn = rbase + ar * 16 + i;
        if (which < 2) {
          Out[((long)((bh << 10) + rowIn) << 6) + d] = f2bf(val);
        } else {
          VbT[((long)((bh << 6) + d) << 10) + rowIn] = f2bf(val);
        }
      }
    }
  }

  if (which < 2) {
    float* norm = (which == 0) ? qn : kn;
#pragma unroll
    for (int off = 1; off < 16; off <<= 1)
#pragma unroll
      for (int ar = 0; ar < 4; ++ar)
#pragma unroll
        for (int i = 0; i < 4; ++i) p2[ar][i] += __shfl_xor(p2[ar][i], off, 64);
    if (lr == 0) {
      float lmin = 3.4e38f;
#pragma unroll
      for (int ar = 0; ar < 4; ++ar) {
#pragma unroll
        for (int i = 0; i < 4; ++i) {
          const int rowIn = rbase + ar * 16 + i;
          const float inv = 1.0f / sqrtf(p2[ar][i]);
          norm[(bh << 10) + rowIn] = (which == 0) ? (inv / TEMPP) : inv;
          lmin = fminf(lmin, inv);
        }
      }
      if (which == 1) atomicMin(&kminU[bh], __float_as_uint(lmin));
    }
  }
}

// swizzled LDS accessor: row stride 2048 B, XOR bits 4..6 with (r&7)
static __device__ __forceinline__ short* sp(short* S, int r, int c) {
  return (short*)((char*)S + (((r << 11) + (c << 1)) ^ ((r & 7) << 4)));
}

// ---------------------------------------------------------------------------
// K2: FUSED scores + STREAMING softmax (swapped-operand QK^T) + dcl stats +
// popcount + PV. Block = 16 query rows of one (b,h). grid (64, 32), 256 thr.
// ---------------------------------------------------------------------------
__global__ __launch_bounds__(256) void k_attn(
    const short* __restrict__ Qb, const short* __restrict__ Kb,
    const short* __restrict__ VbT,
    const float* __restrict__ mask,
    const float* __restrict__ qn, const float* __restrict__ kn,
    const unsigned* __restrict__ kminU,
    float* __restrict__ attn, short* __restrict__ AVb,
    float* __restrict__ partial, float* __restrict__ partial2) {
  __shared__ short S[16 * 1024];   // bf16 ev (unnormalized P), swizzled
  __shared__ float red[4][16][3];  // per-wave per-q partials: Z, alls, pos
  __shared__ float redc[4][16];    // per-wave per-q mask popcount (h==0)
  __shared__ float rowv[16];       // per-row log(alls)-log(pos)
  __shared__ float rowscale[16];   // per-row 1/Z
  __shared__ float rowc[16];
  const int tid = threadIdx.x;
  const int lane = tid & 63;
  const int wv = tid >> 6;
  const int i0 = blockIdx.x * 16;
  const int bh = blockIdx.y;
  const int b = bh >> 3, h = bh & 7;

  const int lr = lane & 15;  // q-row within tile
  const int lk = lane >> 4;  // k-slot group / j-subgroup

  const long qoff = (long)((bh << 10) + i0 + lr) * DHD + lk * 8;
  const bf16x8 q0 = *reinterpret_cast<const bf16x8*>(&Qb[qoff]);
  const bf16x8 q1 = *reinterpret_cast<const bf16x8*>(&Qb[qoff + 32]);
  const short* Kbase = &Kb[(long)(bh << 10) * DHD];
  const float* mrow = mask + ((long)b << 20) + ((long)(i0 + lr) << 10);
  const float* knr = kn + (bh << 10);
  const float inv_qt = qn[(bh << 10) + i0 + lr];  // 1/(||q||*TEMP)
  const float kminv = __uint_as_float(kminU[bh]); // min over j of 1/||k_j||
  const float mlb = (SCALE / TEMPP) / (kminv * inv_qt);  // ||q||*kmax*SCALE
  const float argM = LNEG * SCALE - mlb;

  float Z = 0.f, alls = 0.f, pos = 0.f, cntf = 0.f;
#pragma unroll
  for (int jt = 0; jt < 16; ++jt) {
    const int j0 = wv * 256 + jt * 16;
    const long koff = (long)(j0 + lr) * DHD + lk * 8;
    const bf16x8 k0 = *reinterpret_cast<const bf16x8*>(&Kbase[koff]);
    const bf16x8 k1 = *reinterpret_cast<const bf16x8*>(&Kbase[koff + 32]);
    f32x4 acc = {0.f, 0.f, 0.f, 0.f};
    acc = __builtin_amdgcn_mfma_f32_16x16x32_bf16(k0, q0, acc, 0, 0, 0);
    acc = __builtin_amdgcn_mfma_f32_16x16x32_bf16(k1, q1, acc, 0, 0, 0);
    const int jl = j0 + lk * 4;
    const f32x4 mv = *reinterpret_cast<const f32x4*>(&mrow[jl]);
    const f32x4 kv = *reinterpret_cast<const f32x4*>(&knr[jl]);
    bf16x4 p;
#pragma unroll
    for (int e = 0; e < 4; ++e) {
      const float s = acc[e];
      const bool mset = (mv[e] != 0.0f);
      const float ev = __expf(mset ? (s * SCALE - mlb) : argM);  // <= 1
      const float ec = __expf(__builtin_fmaf(s * inv_qt, kv[e], -1.0f / TEMPP));
      Z += ev;
      alls += ec;
      pos += mset ? ec : 0.0f;
      cntf += mset ? 1.0f : 0.0f;
      p[e] = f2bf(ev);
    }
    *reinterpret_cast<bf16x4*>(sp(S, lr, jl)) = p;
  }
  Z += __shfl_xor(Z, 16, 64);    Z += __shfl_xor(Z, 32, 64);
  alls += __shfl_xor(alls, 16, 64); alls += __shfl_xor(alls, 32, 64);
  pos += __shfl_xor(pos, 16, 64);  pos += __shfl_xor(pos, 32, 64);
  if (lk == 0) { red[wv][lr][0] = Z; red[wv][lr][1] = alls; red[wv][lr][2] = pos; }
  if (h == 0) {
    cntf += __shfl_xor(cntf, 16, 64); cntf += __shfl_xor(cntf, 32, 64);
    if (lk == 0) redc[wv][lr] = cntf;
  }
  __syncthreads();

  const int r = tid >> 4, sub = tid & 15;
  if (sub == 0) {
    const float Zt = red[0][r][0] + red[1][r][0] + red[2][r][0] + red[3][r][0];
    const float at = red[0][r][1] + red[1][r][1] + red[2][r][1] + red[3][r][1];
    const float pt = red[0][r][2] + red[1][r][2] + red[2][r][2] + red[3][r][2];
    rowscale[r] = 1.0f / Zt;
    rowv[r] = __logf(at) - __logf(pt);
    if (h == 0) rowc[r] = redc[0][r] + redc[1][r] + redc[2][r] + redc[3][r];
  }
  __syncthreads();

  const float rZ = rowscale[r];
  float* arow = attn + ((long)bh << 20) + ((long)(i0 + r) << 10);
#pragma unroll
  for (int k = 0; k < 8; ++k) {
    const int c0 = sub * 8 + k * 128;
    const bf16x8 sv = *reinterpret_cast<const bf16x8*>(sp(S, r, c0));
    f32x4 o0, o1;
#pragma unroll
    for (int e = 0; e < 4; ++e) {
      o0[e] = bf2f(sv[e]) * rZ;
      o1[e] = bf2f(sv[4 + e]) * rZ;
    }
    *reinterpret_cast<f32x4*>(&arow[c0]) = o0;
    *reinterpret_cast<f32x4*>(&arow[c0 + 4]) = o1;
  }
  if (tid == 0) {
    float s = 0.f;
#pragma unroll
    for (int i = 0; i < 16; ++i) s += rowv[i];
    partial[bh * 64 + blockIdx.x] = s;
    if (h == 0) {
      float c = 0.f;
#pragma unroll
      for (int i = 0; i < 16; ++i) c += rowc[i];
      partial2[b * 64 + blockIdx.x] = c - 16.0f;  // diag always 1
    }
  }

  f32x4 acc2 = {0.f, 0.f, 0.f, 0.f};
  const short* vrow = &VbT[(long)(bh * DHD + wv * 16 + lr) << 10];
#pragma unroll 8
  for (int k0 = 0; k0 < 32; ++k0) {
    const bf16x8 a = *reinterpret_cast<const bf16x8*>(sp(S, lr, k0 * 32 + lk * 8));
    const bf16x8 bb = *reinterpret_cast<const bf16x8*>(&vrow[k0 * 32 + lk * 8]);
    acc2 = __builtin_amdgcn_mfma_f32_16x16x32_bf16(a, bb, acc2, 0, 0, 0);
  }
#pragma unroll
  for (int i = 0; i < 4; ++i) {
    const int row = lk * 4 + i;
    const float o = acc2[i] * rowscale[row];
    AVb[((long)((b << 10) + i0 + row) << 9) + h * DHD + wv * 16 + lr] = f2bf(o);
  }
}

// ---------------------------------------------------------------------------
// K3: out = AVb @ WoB.T + bo, direct-fragment bf16 GEMM (no LDS/barriers).
// 64x64 tiles, wave w = rows w*16..+15, acc[4] over 64 cols. grid (64, 8).
// ---------------------------------------------------------------------------
__global__ __launch_bounds__(256) void k_outproj2(const short* __restrict__ AVb,
                                                  const short* __restrict__ WoB,
                                                  const float* __restrict__ bo,
                                                  float* __restrict__ out) {
  const int tid = threadIdx.x;
  const int lane = tid & 63;
  const int w = tid >> 6;
  const int lr = lane & 15, lk = lane >> 4;
  const int m0 = blockIdx.x * 64 + w * 16;
  const int n0 = blockIdx.y * 64;
  const short* abase = &AVb[(long)(m0 + lr) * INNERD + lk * 8];
  const short* bbase = &WoB[(long)(n0 + lr) * INNERD + lk * 8];
  const f32x4 z4 = {0.f, 0.f, 0.f, 0.f};
  f32x4 acc[4] = {z4, z4, z4, z4};

  for (int ks = 0; ks < 16; ++ks) {
    const int ko = ks * 32;
    const bf16x8 af = *reinterpret_cast<const bf16x8*>(&abase[ko]);
#pragma unroll
    for (int ac = 0; ac < 4; ++ac) {
      const bf16x8 bf = *reinterpret_cast<const bf16x8*>(&bbase[ac * 16 * INNERD + ko]);
      acc[ac] = __builtin_amdgcn_mfma_f32_16x16x32_bf16(af, bf, acc[ac], 0, 0, 0);
    }
  }
#pragma unroll
  for (int ac = 0; ac < 4; ++ac) {
    const int n = n0 + ac * 16 + lr;
    const float bv = bo[n];
#pragma unroll
    for (int i = 0; i < 4; ++i) {
      const int m = m0 + lk * 4 + i;
      out[((long)m << 9) + n] = acc[ac][i] + bv;
    }
  }
}

// ---------------------------------------------------------------------------
// K4: finalize dcl: reduce 2048 clustering partials + 256 regular partials
// ---------------------------------------------------------------------------
__global__ __launch_bounds__(256) void k_finalize(const float* __restrict__ partial,
                                                  const float* __restrict__ partial2,
                                                  float* __restrict__ dcl) {
  const int tid = threadIdx.x;
  float s = 0.f;
#pragma unroll
  for (int t = 0; t < 8; ++t) s += partial[tid + t * 256];
  float s2 = partial2[tid];
  s = wave_sum(s);
  s2 = wave_sum(s2);
  __shared__ float red[4], red2[4];
  if ((tid & 63) == 0) { red[tid >> 6] = s; red2[tid >> 6] = s2; }
  __syncthreads();
  if (tid == 0) {
    const float cl = red[0] + red[1] + red[2] + red[3];
    const float rg = red2[0] + red2[1] + red2[2] + red2[3];
    *dcl = cl / (float)(NB * NH * NN) + KREG * rg / ((float)NN * (float)(NN - 1)) / (float)NB;
  }
}

extern "C" void kernel_launch(void* const* d_in, const int* in_sizes, int n_in,
                              void* d_out, int out_size, void* d_ws, size_t ws_size,
                              hipStream_t stream) {
  const float* x = (const float*)d_in[0];
  const float* mask = (const float*)d_in[1];
  const float* Wq = (const float*)d_in[2];
  const float* bq = (const float*)d_in[3];
  const float* Wk = (const float*)d_in[4];
  const float* bk = (const float*)d_in[5];
  const float* Wv = (const float*)d_in[6];
  const float* bv = (const float*)d_in[7];
  const float* Wo = (const float*)d_in[8];
  const float* bo = (const float*)d_in[9];

  float* out = (float*)d_out;
  float* attn = out + (size_t)NB * NN * DIMD;
  float* dcl = attn + (size_t)NB * NH * NN * NN;

  char* ws = (char*)d_ws;
  short* Qb = (short*)(ws);                                  // 4 MB (B,H,N,DH)
  short* Kb = (short*)(ws + ((size_t)4 << 20));              // 4 MB
  short* VbT = (short*)(ws + ((size_t)8 << 20));             // 4 MB (B,H,DH,N)
  short* xb = (short*)(ws + ((size_t)12 << 20));             // 4 MB (xb, then AVb)
  short* AVb = xb;                                           // reuse: xb dead after k_qkv2
  short* WB = (short*)(ws + ((size_t)16 << 20));             // 1.5 MB (Wq|Wk|Wv bf16)
  short* WoB = (short*)(ws + ((size_t)16 << 20) + 1572864);  // 0.5 MB
  char* tail = ws + ((size_t)18 << 20);
  float* qn = (float*)(tail);                                // 128 KB
  float* kn = (float*)(tail + (128 << 10));                  // 128 KB
  unsigned* kminU = (unsigned*)(tail + (256 << 10));         // 128 B
  float* partial = (float*)(tail + (320 << 10));             // 8 KB
  float* partial2 = (float*)(tail + (384 << 10));            // 1 KB

  hipMemsetAsync(kminU, 0xFF, 32 * sizeof(unsigned), stream);

  k_pre<<<dim3(3072), 256, 0, stream>>>(x, Wq, Wk, Wv, Wo, xb, WB, WoB);
  k_qkv2<<<dim3(32, 12), 256, 0, stream>>>(xb, WB, bq, bk, bv, Qb, Kb, VbT, qn, kn, kminU);
  k_attn<<<dim3(64, 32), 256, 0, stream>>>(Qb, Kb, VbT, mask, qn, kn, kminU, attn, AVb,
                                           partial, partial2);
  k_outproj2<<<dim3(64, 8), 256, 0, stream>>>(AVb, WoB, bo, out);
  k_finalize<<<1, 256, 0, stream>>>(partial, partial2, dcl);
}